// Round 10
// baseline (146.332 us; speedup 1.0000x reference)
//
#include <hip/hip_runtime.h>

#define TPB 256
#define EPB 8             // elements per block; wave owns 2 (half-wave each in P1-P4)
#define H1S 246           // padded row stride for h1 (245 used; holds 140-vec later)
#define ES  280           // per-element slot: x(256) then h[140]|t30[60]

// ---- d_ws float offsets ----
#define WQ1   0      // 65
#define WQ2   65     // 450
#define WR1Q  515    // 100
#define WR2Q  615    // 100
#define WCQ   715    // 64 (c1 @715, c2 @747)
#define WSB   779    // 474 folded BN
#define SMALL_N 1253
// A-weights, blocked-transposed: [35 float4-col-blocks][140 fused rows] float4
#define WQAT  1280   // 19600
// B-weights, blocked-transposed: [35 float2-col-blocks][60 fused rows] float2
#define WQBT  20880  // 4200

// sb sub-offsets (relative to WSB): [scale[C] | bias[C]] per layer
#define SB_P1 0
#define SB_P2 10
#define SB_R1 30
#define SB_R2 50
#define SB_A1 70
#define SB_B1 210
#define SB_C1 270
#define SB_A2 272
#define SB_B2 412
#define SB_C2 472

// ---------------- prep: quantize weights + fold BN into ws ----------------
#define GFOLD(bn, C, OFF)                                                     \
  if (tid < (C)) {                                                            \
    float gg = (bn)[tid], bb = (bn)[(C) + tid];                               \
    float mm = (bn)[2 * (C) + tid], vv = (bn)[3 * (C) + tid];                 \
    float sc = gg / sqrtf(vv + 1e-5f);                                        \
    sbp[(OFF) + tid] = sc;                                                    \
    sbp[(OFF) + (C) + tid] = bb - mm * sc;                                    \
  }

extern "C" __global__ __launch_bounds__(256)
void prep(const float* __restrict__ w1,  const float* __restrict__ bnp1,
          const float* __restrict__ w2,  const float* __restrict__ bnp2,
          const float* __restrict__ wr1, const float* __restrict__ bnr1,
          const float* __restrict__ wr2, const float* __restrict__ bnr2,
          const float* __restrict__ wa1, const float* __restrict__ bna1,
          const float* __restrict__ wb1, const float* __restrict__ bnb1,
          const float* __restrict__ wc1, const float* __restrict__ bnc1,
          const float* __restrict__ wa2, const float* __restrict__ bna2,
          const float* __restrict__ wb2, const float* __restrict__ bnb2,
          const float* __restrict__ wc2, const float* __restrict__ bnc2,
          float* __restrict__ ws)
{
  __shared__ float s_red[4];
  const int tid = threadIdx.x;
  const int b = blockIdx.x;

  if (b == 10) {  // fold all BN params
    float* sbp = ws + WSB;
    GFOLD(bnp1, 5, SB_P1)  GFOLD(bnp2, 10, SB_P2)
    GFOLD(bnr1, 10, SB_R1) GFOLD(bnr2, 10, SB_R2)
    GFOLD(bna1, 70, SB_A1) GFOLD(bnb1, 30, SB_B1) GFOLD(bnc1, 1, SB_C1)
    GFOLD(bna2, 70, SB_A2) GFOLD(bnb2, 30, SB_B2) GFOLD(bnc2, 1, SB_C2)
    return;
  }

  const float* src; int n; int mode; int rofs; float* dst = ws;
  int ofs = 0;
  switch (b) {
    case 0: src = w1;  ofs = WQ1;      n = 65;   mode = 0; rofs = 0;  break;
    case 1: src = w2;  ofs = WQ2;      n = 450;  mode = 0; rofs = 0;  break;
    case 2: src = wr1; ofs = WR1Q;     n = 100;  mode = 0; rofs = 0;  break;
    case 3: src = wr2; ofs = WR2Q;     n = 100;  mode = 0; rofs = 0;  break;
    case 4: src = wa1; ofs = WQAT;     n = 9800; mode = 1; rofs = 0;  break;
    case 5: src = wb1; ofs = WQBT;     n = 2100; mode = 2; rofs = 0;  break;
    case 6: src = wc1; ofs = WCQ;      n = 30;   mode = 0; rofs = 0;  break;
    case 7: src = wa2; ofs = WQAT;     n = 9800; mode = 1; rofs = 70; break;
    case 8: src = wb2; ofs = WQBT;     n = 2100; mode = 2; rofs = 30; break;
    default:src = wc2; ofs = WCQ + 32; n = 30;   mode = 0; rofs = 0;  break;
  }

  float m = 0.f;
  for (int i = tid; i < n; i += 256) m = fmaxf(m, fabsf(src[i]));
#pragma unroll
  for (int off = 32; off > 0; off >>= 1)
    m = fmaxf(m, __shfl_down(m, off, 64));
  if ((tid & 63) == 0) s_red[tid >> 6] = m;
  __syncthreads();
  m = fmaxf(fmaxf(s_red[0], s_red[1]), fmaxf(s_red[2], s_red[3]));

  float s = m / 127.0f;
  for (int i = tid; i < n; i += 256) {
    float w = src[i];
    float q = rintf(fminf(fmaxf(w / s, -127.f), 127.f)) * s;
    if (mode == 0) {
      dst[ofs + i] = q;
    } else if (mode == 1) {           // A: row r, col c -> [c/4][r] float4
      int r = i / 140 + rofs, c = i % 140;
      dst[ofs + ((c >> 2) * 140 + r) * 4 + (c & 3)] = q;
    } else {                          // B: row r, col c -> [c/2][r] float2
      int r = i / 70 + rofs, c = i % 70;
      dst[ofs + ((c >> 1) * 60 + r) * 2 + (c & 1)] = q;
    }
  }
}

// -------- main pipeline: wave owns 2 elements, ZERO barriers --------------
// LDS-pipe pressure minimized: P2-P4 carried in registers (lane = ow, co
// loops uniform -> weights/BN via SCALAR s_loads from ws); A-phase cb-outer
// so the per-element h vector is LDS-read once per cb (70 b128 vs 210).
extern "C" __global__ __launch_bounds__(TPB, 4)
void taunet(const float* __restrict__ x, const float* __restrict__ ws,
            float* __restrict__ out, int B)
{
  __shared__ __align__(16) float s_h1[EPB * H1S];   // pre1 out; later 140-vec
  __shared__ __align__(16) float s_e[EPB * ES];     // x -> h[140]|t30[60]
  __shared__ __align__(16) float s_small[SMALL_N];  // only [WCQ..) staged

  const int tid = threadIdx.x;
  const int g  = tid >> 5;    // element slot within block (half-wave)
  const int l  = tid & 31;    // lane within element (P1-P4, C)
  const int ln = tid & 63;    // lane within wave
  const int wv = tid >> 6;    // wave within block
  const int gp = 2 * wv;      // wave's first element slot
  const int elem = blockIdx.x * EPB + g;

  // stage only the lane-varying constants (A/B sb lookups, C weights)
  for (int i = WCQ + ln; i < SMALL_N; i += 64) s_small[i] = ws[i];

  // stage x: wave stages its own two elements (coalesced float4)
  {
    const float4* xb = (const float4*)x;
#pragma unroll
    for (int it = 0; it < 2; ++it) {
      int e = gp + it;
      int ge = blockIdx.x * EPB + e;
      if (ge < B) {
        float4 v = xb[ge * 64 + ln];
        *(float4*)&s_e[e * ES + ln * 4] = v;
      }
    }
  }

  // ---- P1: pre1 (Cin=1, K=13, stride 5) -> h1[5][49] in LDS ----
  // weights + BN are wave-uniform ws[] reads -> scalar loads (SMEM pipe)
  {
    const float* xe = &s_e[g * ES];
#pragma unroll
    for (int rep = 0; rep < 2; ++rep) {
      int p = l + 32 * rep;
      bool act = p < 49;
      int ps = act ? p : 0;
      float win[13];
#pragma unroll
      for (int k = 0; k < 13; ++k) win[k] = xe[5 * ps + k];
#pragma unroll
      for (int ci = 0; ci < 5; ++ci) {
        float a0 = 0.f, a1 = 0.f;
#pragma unroll
        for (int k = 0; k < 13; ++k) {
          float d = fabsf(win[k] - ws[WQ1 + ci * 13 + k]);
          if (k & 1) a1 += d; else a0 += d;
        }
        float v = fmaxf(fmaf(-(a0 + a1), ws[WSB + SB_P1 + ci],
                             ws[WSB + SB_P1 + 5 + ci]), 0.f);
        if (act) s_h1[g * H1S + ci * 49 + ps] = v;
      }
    }
  }

  // ---- P2: pre2 -> h2 in REGISTERS (lane = ow, 14 active; co uniform) ----
  float h2r[10];
  {
    const bool act = l < 14;
    const int ow = act ? l : 0;
    const float* h1b = &s_h1[g * H1S];
    float acc[10] = {0.f,0.f,0.f,0.f,0.f,0.f,0.f,0.f,0.f,0.f};
#pragma unroll
    for (int ci = 0; ci < 5; ++ci) {
      float w9[9];
#pragma unroll
      for (int k = 0; k < 9; ++k) w9[k] = h1b[ci * 49 + 3 * ow + k];
#pragma unroll
      for (int co = 0; co < 10; ++co) {
        float s0 = 0.f, s1 = 0.f;
#pragma unroll
        for (int k = 0; k < 9; ++k) {
          float d = fabsf(w9[k] - ws[WQ2 + co * 45 + ci * 9 + k]);
          if (k & 1) s1 += d; else s0 += d;
        }
        acc[co] += s0 + s1;
      }
    }
#pragma unroll
    for (int co = 0; co < 10; ++co)
      h2r[co] = fmaxf(fmaf(-acc[co], ws[WSB + SB_P2 + co],
                           ws[WSB + SB_P2 + 10 + co]), 0.f);
  }

  // ---- P3: r1 + relu, all in registers ----
  float t1r[10];
#pragma unroll
  for (int co = 0; co < 10; ++co) {
    float a0 = 0.f, a1 = 0.f;
#pragma unroll
    for (int ci = 0; ci < 10; ++ci) {
      float d = fabsf(h2r[ci] - ws[WR1Q + co * 10 + ci]);
      if (ci & 1) a1 += d; else a0 += d;
    }
    t1r[co] = fmaxf(fmaf(-(a0 + a1), ws[WSB + SB_R1 + co],
                         ws[WSB + SB_R1 + 10 + co]), 0.f);
  }

  // ---- P4: r2 + residual; h = relu(t2 + h2) -> LDS (for A broadcast) ----
#pragma unroll
  for (int co = 0; co < 10; ++co) {
    float a0 = 0.f, a1 = 0.f;
#pragma unroll
    for (int ci = 0; ci < 10; ++ci) {
      float d = fabsf(t1r[ci] - ws[WR2Q + co * 10 + ci]);
      if (ci & 1) a1 += d; else a0 += d;
    }
    float t2 = fmaf(-(a0 + a1), ws[WSB + SB_R2 + co], ws[WSB + SB_R2 + 10 + co]);
    float h = fmaxf(t2 + h2r[co], 0.f);
    if (l < 14) s_e[g * ES + co * 14 + l] = h;
  }

  // ---- A/B fused branches, wave-wide ----
  {
    const float* hb0 = &s_e[gp * ES];         // element e0 = gp
    const float* hb1 = &s_e[(gp + 1) * ES];   // element e1 = gp+1

    // A: cb-outer; h4/k4 LDS-read ONCE per cb; 3 row-sets accumulate in regs.
    // unroll capped at 2 (VGPR/spill discipline — R3/R4/R6 lessons).
    const int r2 = (ln + 128 > 139) ? 139 : ln + 128;
    float accA[3][4], accB[3][4];
#pragma unroll
    for (int p = 0; p < 3; ++p)
#pragma unroll
      for (int j = 0; j < 4; ++j) { accA[p][j] = 0.f; accB[p][j] = 0.f; }
    const int rows[3] = {ln, ln + 64, r2};
#pragma unroll 2
    for (int cb = 0; cb < 35; ++cb) {
      float4 h4 = *(const float4*)&hb0[cb * 4];
      float4 k4 = *(const float4*)&hb1[cb * 4];
#pragma unroll
      for (int p = 0; p < 3; ++p) {
        float4 w4 = *(const float4*)&ws[WQAT + (cb * 140 + rows[p]) * 4];
        accA[p][0] += fabsf(h4.x - w4.x);
        accA[p][1] += fabsf(h4.y - w4.y);
        accA[p][2] += fabsf(h4.z - w4.z);
        accA[p][3] += fabsf(h4.w - w4.w);
        accB[p][0] += fabsf(k4.x - w4.x);
        accB[p][1] += fabsf(k4.y - w4.y);
        accB[p][2] += fabsf(k4.z - w4.z);
        accB[p][3] += fabsf(k4.w - w4.w);
      }
    }
#pragma unroll
    for (int p = 0; p < 3; ++p) {
      int cl = rows[p];
      bool act = (p < 2) || (ln < 12);
      if (act) {
        int co  = cl < 70 ? cl : cl - 70;
        int off = cl < 70 ? SB_A1 : SB_A2;
        float sc = s_small[WSB + off + co], bi = s_small[WSB + off + 70 + co];
        float sadA = (accA[p][0] + accA[p][1]) + (accA[p][2] + accA[p][3]);
        float sadB = (accB[p][0] + accB[p][1]) + (accB[p][2] + accB[p][3]);
        s_h1[gp * H1S + cl]       = fmaxf(fmaf(-sadA, sc, bi), 0.f);
        s_h1[(gp + 1) * H1S + cl] = fmaxf(fmaf(-sadB, sc, bi), 0.f);
      }
    }

    // B: 60 fused rows in one pass; dense float2 weight loads
    {
      bool act = ln < 60;
      int rl = act ? ln : 0;
      int br = rl >= 30;
      int co = br ? rl - 30 : rl;
      const float* h0 = &s_h1[gp * H1S + br * 70];
      const float* h1 = &s_h1[(gp + 1) * H1S + br * 70];
      int off = br ? SB_B2 : SB_B1;
      float a0 = 0.f, a1 = 0.f, b0 = 0.f, b1 = 0.f;
#pragma unroll 8
      for (int ci = 0; ci < 35; ++ci) {
        float2 w2v = *(const float2*)&ws[WQBT + (ci * 60 + rl) * 2];
        a0 += fabsf(h0[2 * ci]     - w2v.x);
        a1 += fabsf(h0[2 * ci + 1] - w2v.y);
        b0 += fabsf(h1[2 * ci]     - w2v.x);
        b1 += fabsf(h1[2 * ci + 1] - w2v.y);
      }
      if (act) {
        float sc = s_small[WSB + off + co], bi = s_small[WSB + off + 30 + co];
        s_e[gp * ES + 140 + rl]       = fmaxf(fmaf(-(a0 + a1), sc, bi), 0.f);
        s_e[(gp + 1) * ES + 140 + rl] = fmaxf(fmaf(-(b0 + b1), sc, bi), 0.f);
      }
    }

    // C: per element (half-wave), both branches sequentially; width-32 tree
    for (int br = 0; br < 2; ++br) {
      float d = 0.f;
      if (l < 30)
        d = fabsf(s_e[g * ES + 140 + br * 30 + l] - s_small[WCQ + br * 32 + l]);
#pragma unroll
      for (int off = 16; off > 0; off >>= 1)
        d += __shfl_down(d, off, 32);
      if (l == 0 && elem < B) {
        int sbC = br ? SB_C2 : SB_C1;
        out[br * B + elem] =
            fmaxf(fmaf(-d, ws[WSB + sbC], ws[WSB + sbC + 1]), 0.f);
      }
    }
  }
}

extern "C" void kernel_launch(void* const* d_in, const int* in_sizes, int n_in,
                              void* d_out, int out_size, void* d_ws, size_t ws_size,
                              hipStream_t stream) {
  const float* x    = (const float*)d_in[0];
  const float* w1   = (const float*)d_in[1];
  const float* bnp1 = (const float*)d_in[2];
  const float* w2   = (const float*)d_in[3];
  const float* bnp2 = (const float*)d_in[4];
  const float* wr1  = (const float*)d_in[5];
  const float* bnr1 = (const float*)d_in[6];
  const float* wr2  = (const float*)d_in[7];
  const float* bnr2 = (const float*)d_in[8];
  const float* wa1  = (const float*)d_in[9];
  const float* bna1 = (const float*)d_in[10];
  const float* wb1  = (const float*)d_in[11];
  const float* bnb1 = (const float*)d_in[12];
  const float* wc1  = (const float*)d_in[13];
  const float* bnc1 = (const float*)d_in[14];
  const float* wa2  = (const float*)d_in[15];
  const float* bna2 = (const float*)d_in[16];
  const float* wb2  = (const float*)d_in[17];
  const float* bnb2 = (const float*)d_in[18];
  const float* wc2  = (const float*)d_in[19];
  const float* bnc2 = (const float*)d_in[20];

  float* ws = (float*)d_ws;
  int B = in_sizes[0] / 256;
  int blocks = (B + EPB - 1) / EPB;

  hipLaunchKernelGGL(prep, dim3(11), dim3(256), 0, stream,
                     w1, bnp1, w2, bnp2, wr1, bnr1, wr2, bnr2,
                     wa1, bna1, wb1, bnb1, wc1, bnc1,
                     wa2, bna2, wb2, bnb2, wc2, bnc2, ws);

  hipLaunchKernelGGL(taunet, dim3(blocks), dim3(TPB), 0, stream,
                     x, ws, (float*)d_out, B);
}

// Round 11
// 136.562 us; speedup vs baseline: 1.0715x; 1.0715x over previous
//
#include <hip/hip_runtime.h>

#define TPB 256
#define EPB 8             // elements per block; wave owns 2 (half-wave each in P1-P4)
#define H1S 246           // padded row stride for h1 (245 used; holds 140-vec later)
#define ES  280           // per-element slot: x(256) then h[140]|t30[60]

// ---- d_ws float offsets ----
#define WQ1   0      // 65
#define WQ2   65     // 450
#define WR1Q  515    // 100
#define WR2Q  615    // 100
#define WCQ   715    // 64 (c1 @715, c2 @747)
#define WSB   779    // 474 folded BN
#define SMALL_N 1253
// A-weights, blocked-transposed: [35 float4-col-blocks][140 fused rows] float4
#define WQAT  1280   // 19600
// B-weights, blocked-transposed: [35 float2-col-blocks][60 fused rows] float2
#define WQBT  20880  // 4200

// sb sub-offsets (relative to WSB): [scale[C] | bias[C]] per layer
#define SB_P1 0
#define SB_P2 10
#define SB_R1 30
#define SB_R2 50
#define SB_A1 70
#define SB_B1 210
#define SB_C1 270
#define SB_A2 272
#define SB_B2 412
#define SB_C2 472

// ---------------- prep: quantize weights + fold BN into ws ----------------
#define GFOLD(bn, C, OFF)                                                     \
  if (tid < (C)) {                                                            \
    float gg = (bn)[tid], bb = (bn)[(C) + tid];                               \
    float mm = (bn)[2 * (C) + tid], vv = (bn)[3 * (C) + tid];                 \
    float sc = gg / sqrtf(vv + 1e-5f);                                        \
    sbp[(OFF) + tid] = sc;                                                    \
    sbp[(OFF) + (C) + tid] = bb - mm * sc;                                    \
  }

extern "C" __global__ __launch_bounds__(256)
void prep(const float* __restrict__ w1,  const float* __restrict__ bnp1,
          const float* __restrict__ w2,  const float* __restrict__ bnp2,
          const float* __restrict__ wr1, const float* __restrict__ bnr1,
          const float* __restrict__ wr2, const float* __restrict__ bnr2,
          const float* __restrict__ wa1, const float* __restrict__ bna1,
          const float* __restrict__ wb1, const float* __restrict__ bnb1,
          const float* __restrict__ wc1, const float* __restrict__ bnc1,
          const float* __restrict__ wa2, const float* __restrict__ bna2,
          const float* __restrict__ wb2, const float* __restrict__ bnb2,
          const float* __restrict__ wc2, const float* __restrict__ bnc2,
          float* __restrict__ ws)
{
  __shared__ float s_red[4];
  const int tid = threadIdx.x;
  const int b = blockIdx.x;

  if (b == 10) {  // fold all BN params
    float* sbp = ws + WSB;
    GFOLD(bnp1, 5, SB_P1)  GFOLD(bnp2, 10, SB_P2)
    GFOLD(bnr1, 10, SB_R1) GFOLD(bnr2, 10, SB_R2)
    GFOLD(bna1, 70, SB_A1) GFOLD(bnb1, 30, SB_B1) GFOLD(bnc1, 1, SB_C1)
    GFOLD(bna2, 70, SB_A2) GFOLD(bnb2, 30, SB_B2) GFOLD(bnc2, 1, SB_C2)
    return;
  }

  const float* src; int n; int mode; int rofs; float* dst = ws;
  int ofs = 0;
  switch (b) {
    case 0: src = w1;  ofs = WQ1;      n = 65;   mode = 0; rofs = 0;  break;
    case 1: src = w2;  ofs = WQ2;      n = 450;  mode = 0; rofs = 0;  break;
    case 2: src = wr1; ofs = WR1Q;     n = 100;  mode = 0; rofs = 0;  break;
    case 3: src = wr2; ofs = WR2Q;     n = 100;  mode = 0; rofs = 0;  break;
    case 4: src = wa1; ofs = WQAT;     n = 9800; mode = 1; rofs = 0;  break;
    case 5: src = wb1; ofs = WQBT;     n = 2100; mode = 2; rofs = 0;  break;
    case 6: src = wc1; ofs = WCQ;      n = 30;   mode = 0; rofs = 0;  break;
    case 7: src = wa2; ofs = WQAT;     n = 9800; mode = 1; rofs = 70; break;
    case 8: src = wb2; ofs = WQBT;     n = 2100; mode = 2; rofs = 30; break;
    default:src = wc2; ofs = WCQ + 32; n = 30;   mode = 0; rofs = 0;  break;
  }

  float m = 0.f;
  for (int i = tid; i < n; i += 256) m = fmaxf(m, fabsf(src[i]));
#pragma unroll
  for (int off = 32; off > 0; off >>= 1)
    m = fmaxf(m, __shfl_down(m, off, 64));
  if ((tid & 63) == 0) s_red[tid >> 6] = m;
  __syncthreads();
  m = fmaxf(fmaxf(s_red[0], s_red[1]), fmaxf(s_red[2], s_red[3]));

  float s = m / 127.0f;
  for (int i = tid; i < n; i += 256) {
    float w = src[i];
    float q = rintf(fminf(fmaxf(w / s, -127.f), 127.f)) * s;
    if (mode == 0) {
      dst[ofs + i] = q;
    } else if (mode == 1) {           // A: row r, col c -> [c/4][r] float4
      int r = i / 140 + rofs, c = i % 140;
      dst[ofs + ((c >> 2) * 140 + r) * 4 + (c & 3)] = q;
    } else {                          // B: row r, col c -> [c/2][r] float2
      int r = i / 70 + rofs, c = i % 70;
      dst[ofs + ((c >> 1) * 60 + r) * 2 + (c & 1)] = q;
    }
  }
}

// -------- main pipeline: wave owns 2 elements, ZERO barriers --------------
// R11 = R9 lane layouts (P2-P4 half-wave, 28-32 active lanes) + R10's
// LDS-lean A-phase (cb-outer: h read ONCE per cb -> 70 vs 210 b128) and
// scalar-s_load P1 weights. Best-of-both after R10's post-mortem showed
// the P2-P4 register rewrite doubled VALU math while A/P1 cuts helped.
extern "C" __global__ __launch_bounds__(TPB, 4)
void taunet(const float* __restrict__ x, const float* __restrict__ ws,
            float* __restrict__ out, int B)
{
  __shared__ __align__(16) float s_h1[EPB * H1S];   // pre1 out; later 140-vec
  __shared__ __align__(16) float s_e[EPB * ES];     // x -> h[140]|t30[60]
  __shared__ __align__(16) float s_small[SMALL_N];

  const int tid = threadIdx.x;
  const int g  = tid >> 5;    // element slot within block (half-wave)
  const int l  = tid & 31;    // lane within element (P1-P4, C)
  const int ln = tid & 63;    // lane within wave
  const int wv = tid >> 6;    // wave within block
  const int gp = 2 * wv;      // wave's first element slot
  const int elem = blockIdx.x * EPB + g;

  // per-wave redundant copy of small weights+BN (identical values -> benign
  // race; each wave's own writes are ordered before its reads => no barrier)
  for (int i = ln; i < SMALL_N; i += 64) s_small[i] = ws[i];

  // stage x: wave stages its own two elements (coalesced float4)
  {
    const float4* xb = (const float4*)x;
#pragma unroll
    for (int it = 0; it < 2; ++it) {
      int e = gp + it;
      int ge = blockIdx.x * EPB + e;
      if (ge < B) {
        float4 v = xb[ge * 64 + ln];
        *(float4*)&s_e[e * ES + ln * 4] = v;
      }
    }
  }

  const float* sb = &s_small[WSB];

  // ---- P1: pre1 (Cin=1, K=13, stride 5) -> h1[5][49] ----
  // weights + BN wave-uniform from ws[] -> scalar s_loads (SMEM pipe)
  {
    const float* xe = &s_e[g * ES];
#pragma unroll
    for (int rep = 0; rep < 2; ++rep) {
      int p = l + 32 * rep;
      bool act = p < 49;
      int ps = act ? p : 0;
      float win[13];
#pragma unroll
      for (int k = 0; k < 13; ++k) win[k] = xe[5 * ps + k];
#pragma unroll
      for (int ci = 0; ci < 5; ++ci) {
        float a0 = 0.f, a1 = 0.f;
#pragma unroll
        for (int k = 0; k < 13; ++k) {
          float d = fabsf(win[k] - ws[WQ1 + ci * 13 + k]);
          if (k & 1) a1 += d; else a0 += d;
        }
        float v = fmaxf(fmaf(-(a0 + a1), ws[WSB + SB_P1 + ci],
                             ws[WSB + SB_P1 + 5 + ci]), 0.f);
        if (act) s_h1[g * H1S + ci * 49 + ps] = v;
      }
    }
  }

  // ---- P2: pre2 (Cin=5, K=9, stride 3) -> h2[10][14] ----
  // half-wave: lane = ow(14 of 16) x co-half(2); ci-outer, 9-reg window
  {
    const int ch = l >> 4;
    const int ow16 = l & 15;
    const bool act = ow16 < 14;
    const int ow = act ? ow16 : 0;
    const float* h1b = &s_h1[g * H1S];
    float acc[5] = {0.f, 0.f, 0.f, 0.f, 0.f};
#pragma unroll
    for (int ci = 0; ci < 5; ++ci) {
      float w9[9];
#pragma unroll
      for (int k = 0; k < 9; ++k) w9[k] = h1b[ci * 49 + 3 * ow + k];
#pragma unroll
      for (int c = 0; c < 5; ++c) {
        int co = ch * 5 + c;
        float s0 = 0.f, s1 = 0.f;
#pragma unroll
        for (int k = 0; k < 9; ++k) {
          float d = fabsf(w9[k] - s_small[WQ2 + co * 45 + ci * 9 + k]);
          if (k & 1) s1 += d; else s0 += d;
        }
        acc[c] += s0 + s1;
      }
    }
#pragma unroll
    for (int c = 0; c < 5; ++c) {
      int co = ch * 5 + c;
      float v = fmaxf(fmaf(-acc[c], sb[SB_P2 + co], sb[SB_P2 + 10 + co]), 0.f);
      if (act) s_e[g * ES + co * 14 + ow] = v;
    }
  }

  // ---- P3: r1 (10x10, K=1) + relu -> t1 ----
#pragma unroll
  for (int j = 0; j < 5; ++j) {
    int idx = l + 32 * j;
    if (idx < 140) {
      int co = idx / 14, ow = idx % 14;
      float a0 = 0.f, a1 = 0.f;
#pragma unroll
      for (int ci = 0; ci < 10; ++ci) {
        float d = fabsf(s_e[g * ES + ci * 14 + ow] - s_small[WR1Q + co * 10 + ci]);
        if (ci & 1) a1 += d; else a0 += d;
      }
      s_e[g * ES + 140 + idx] =
          fmaxf(fmaf(-(a0 + a1), sb[SB_R1 + co], sb[SB_R1 + 10 + co]), 0.f);
    }
  }

  // ---- P4: r2 (no relu) + residual, h = relu(t2 + h2), in place ----
#pragma unroll
  for (int j = 0; j < 5; ++j) {
    int idx = l + 32 * j;
    if (idx < 140) {
      int co = idx / 14, ow = idx % 14;
      float a0 = 0.f, a1 = 0.f;
#pragma unroll
      for (int ci = 0; ci < 10; ++ci) {
        float d = fabsf(s_e[g * ES + 140 + ci * 14 + ow] - s_small[WR2Q + co * 10 + ci]);
        if (ci & 1) a1 += d; else a0 += d;
      }
      float t2 = fmaf(-(a0 + a1), sb[SB_R2 + co], sb[SB_R2 + 10 + co]);
      s_e[g * ES + idx] = fmaxf(t2 + s_e[g * ES + idx], 0.f);
    }
  }

  // ---- A/B fused branches, wave-wide ----
  {
    const float* hb0 = &s_e[gp * ES];         // element e0 = gp
    const float* hb1 = &s_e[(gp + 1) * ES];   // element e1 = gp+1

    // A: cb-outer; h4/k4 LDS-read ONCE per cb (70 b128/wave vs 210);
    // 3 row-sets accumulate in 24 regs. unroll 2 (spill discipline).
    const int r2 = (ln + 128 > 139) ? 139 : ln + 128;
    const int rows[3] = {ln, ln + 64, r2};
    float accA[3][4], accB[3][4];
#pragma unroll
    for (int p = 0; p < 3; ++p)
#pragma unroll
      for (int j = 0; j < 4; ++j) { accA[p][j] = 0.f; accB[p][j] = 0.f; }
#pragma unroll 2
    for (int cb = 0; cb < 35; ++cb) {
      float4 h4 = *(const float4*)&hb0[cb * 4];
      float4 k4 = *(const float4*)&hb1[cb * 4];
#pragma unroll
      for (int p = 0; p < 3; ++p) {
        float4 w4 = *(const float4*)&ws[WQAT + (cb * 140 + rows[p]) * 4];
        accA[p][0] += fabsf(h4.x - w4.x);
        accA[p][1] += fabsf(h4.y - w4.y);
        accA[p][2] += fabsf(h4.z - w4.z);
        accA[p][3] += fabsf(h4.w - w4.w);
        accB[p][0] += fabsf(k4.x - w4.x);
        accB[p][1] += fabsf(k4.y - w4.y);
        accB[p][2] += fabsf(k4.z - w4.z);
        accB[p][3] += fabsf(k4.w - w4.w);
      }
    }
#pragma unroll
    for (int p = 0; p < 3; ++p) {
      int cl = rows[p];
      bool act = (p < 2) || (ln < 12);
      if (act) {
        int co  = cl < 70 ? cl : cl - 70;
        int off = cl < 70 ? SB_A1 : SB_A2;
        float sc = sb[off + co], bi = sb[off + 70 + co];
        float sadA = (accA[p][0] + accA[p][1]) + (accA[p][2] + accA[p][3]);
        float sadB = (accB[p][0] + accB[p][1]) + (accB[p][2] + accB[p][3]);
        s_h1[gp * H1S + cl]       = fmaxf(fmaf(-sadA, sc, bi), 0.f);
        s_h1[(gp + 1) * H1S + cl] = fmaxf(fmaf(-sadB, sc, bi), 0.f);
      }
    }

    // B: 60 fused rows in one pass; dense float2 weight loads
    {
      bool act = ln < 60;
      int rl = act ? ln : 0;
      int br = rl >= 30;
      int co = br ? rl - 30 : rl;
      const float* h0 = &s_h1[gp * H1S + br * 70];
      const float* h1 = &s_h1[(gp + 1) * H1S + br * 70];
      int off = br ? SB_B2 : SB_B1;
      float a0 = 0.f, a1 = 0.f, b0 = 0.f, b1 = 0.f;
#pragma unroll 8
      for (int ci = 0; ci < 35; ++ci) {
        float2 w2v = *(const float2*)&ws[WQBT + (ci * 60 + rl) * 2];
        a0 += fabsf(h0[2 * ci]     - w2v.x);
        a1 += fabsf(h0[2 * ci + 1] - w2v.y);
        b0 += fabsf(h1[2 * ci]     - w2v.x);
        b1 += fabsf(h1[2 * ci + 1] - w2v.y);
      }
      if (act) {
        float sc = sb[off + co], bi = sb[off + 30 + co];
        s_e[gp * ES + 140 + rl]       = fmaxf(fmaf(-(a0 + a1), sc, bi), 0.f);
        s_e[(gp + 1) * ES + 140 + rl] = fmaxf(fmaf(-(b0 + b1), sc, bi), 0.f);
      }
    }

    // C: per element (half-wave), both branches sequentially; width-32 tree
    for (int br = 0; br < 2; ++br) {
      float d = 0.f;
      if (l < 30)
        d = fabsf(s_e[g * ES + 140 + br * 30 + l] - s_small[WCQ + br * 32 + l]);
#pragma unroll
      for (int off = 16; off > 0; off >>= 1)
        d += __shfl_down(d, off, 32);
      if (l == 0 && elem < B) {
        int sbC = br ? SB_C2 : SB_C1;
        out[br * B + elem] = fmaxf(fmaf(-d, sb[sbC], sb[sbC + 1]), 0.f);
      }
    }
  }
}

extern "C" void kernel_launch(void* const* d_in, const int* in_sizes, int n_in,
                              void* d_out, int out_size, void* d_ws, size_t ws_size,
                              hipStream_t stream) {
  const float* x    = (const float*)d_in[0];
  const float* w1   = (const float*)d_in[1];
  const float* bnp1 = (const float*)d_in[2];
  const float* w2   = (const float*)d_in[3];
  const float* bnp2 = (const float*)d_in[4];
  const float* wr1  = (const float*)d_in[5];
  const float* bnr1 = (const float*)d_in[6];
  const float* wr2  = (const float*)d_in[7];
  const float* bnr2 = (const float*)d_in[8];
  const float* wa1  = (const float*)d_in[9];
  const float* bna1 = (const float*)d_in[10];
  const float* wb1  = (const float*)d_in[11];
  const float* bnb1 = (const float*)d_in[12];
  const float* wc1  = (const float*)d_in[13];
  const float* bnc1 = (const float*)d_in[14];
  const float* wa2  = (const float*)d_in[15];
  const float* bna2 = (const float*)d_in[16];
  const float* wb2  = (const float*)d_in[17];
  const float* bnb2 = (const float*)d_in[18];
  const float* wc2  = (const float*)d_in[19];
  const float* bnc2 = (const float*)d_in[20];

  float* ws = (float*)d_ws;
  int B = in_sizes[0] / 256;
  int blocks = (B + EPB - 1) / EPB;

  hipLaunchKernelGGL(prep, dim3(11), dim3(256), 0, stream,
                     w1, bnp1, w2, bnp2, wr1, bnr1, wr2, bnr2,
                     wa1, bna1, wb1, bnb1, wc1, bnc1,
                     wa2, bna2, wb2, bnb2, wc2, bnc2, ws);

  hipLaunchKernelGGL(taunet, dim3(blocks), dim3(TPB), 0, stream,
                     x, ws, (float*)d_out, B);
}